// Round 12
// baseline (100.810 us; speedup 1.0000x reference)
//
#include <hip/hip_runtime.h>

#define N_NODES 100000
#define N_EDGES 600000
#define D 128
#define M_PAD 100096            // 782 * 128

#define NB   196                // buckets = tgt >> 9
#define BWID 512                // nodes per bucket
#define NCH  196                // edge chunks
#define CE   3062               // edges per chunk (last: 2910)

typedef unsigned int uint32;
typedef unsigned long long uint64;
typedef __attribute__((ext_vector_type(8))) short short8;
typedef __attribute__((ext_vector_type(4))) float f32x4;

__device__ __forceinline__ uint32 f2bf(float x) {          // RNE f32 -> bf16
    uint32 u = __float_as_uint(x);
    return (u + 0x7FFFu + ((u >> 16) & 1u)) >> 16;
}
__device__ __forceinline__ float bflo(uint32 u) { return __uint_as_float(u << 16); }
__device__ __forceinline__ float bfhi(uint32 u) { return __uint_as_float(u & 0xFFFF0000u); }

// ---------------------------------------------------------------------------
// K1: convert nf -> bf16 upper K-half of Abuf (grid-stride, 1024 blocks);
// blocks 0..195 also count their edge-chunk's bucket histogram in LDS and
// store as plain u64 (flag bit 32 = 0). Block 1023 zeroes aggregate flags.
// ---------------------------------------------------------------------------
__global__ __launch_bounds__(256) void k1_convert_count(
        const float* __restrict__ nf, unsigned short* __restrict__ Abuf,
        const int* __restrict__ edges, uint64* __restrict__ cntmat,
        uint64* __restrict__ flags) {
    __shared__ uint32 c[NB];
    const int tid = threadIdx.x;
    const int bid = blockIdx.x;

    if (bid == 1023 && tid < NB) flags[tid] = 0ULL;

    for (int idx = bid * 256 + tid; idx < N_NODES * 16; idx += 1024 * 256) {
        int r = idx >> 4;
        int ccol = (idx & 15) * 8;
        const float4 v0 = *reinterpret_cast<const float4*>(nf + (size_t)r * D + ccol);
        const float4 v1 = *reinterpret_cast<const float4*>(nf + (size_t)r * D + ccol + 4);
        uint4 w;
        w.x = f2bf(v0.x) | (f2bf(v0.y) << 16);
        w.y = f2bf(v0.z) | (f2bf(v0.w) << 16);
        w.z = f2bf(v1.x) | (f2bf(v1.y) << 16);
        w.w = f2bf(v1.z) | (f2bf(v1.w) << 16);
        *reinterpret_cast<uint4*>(Abuf + (size_t)r * 256 + D + ccol) = w;
    }

    if (bid < NCH) {
        for (int i = tid; i < NB; i += 256) c[i] = 0u;
        __syncthreads();
        const int e0 = bid * CE;
        const int e1 = (e0 + CE < N_EDGES) ? e0 + CE : N_EDGES;
        for (int e = e0 + tid; e < e1; e += 256) {
            int tgt = edges[N_EDGES + e];
            atomicAdd(&c[tgt >> 9], 1u);               // LDS atomic
        }
        __syncthreads();
        for (int i = tid; i < NB; i += 256)
            cntmat[(size_t)i * NCH + bid] = (uint64)c[i];   // bucket-major, flag=0
    }
}

// ---------------------------------------------------------------------------
// K23 (merged scan + bucket scatter), 196 blocks:
//  scan: block b scans bucket-row b, publishes total via packed-u64 agg flag,
//        polls predecessors, atomicExch's flagged scanned bases (bit 32).
//  scatter: block b (as chunk b) polls its base column (per-entry flags),
//        then scatters packed (lt<<17|src) pairs via LDS-atomic ranks.
//  Idle width does W-prep + bias fuse. All cross-block data moves via
//  atomics (packed value+flag) -> safe under XCD non-coherence.
// ---------------------------------------------------------------------------
__global__ __launch_bounds__(256) void k23_scan_bucket(
        const int* __restrict__ edges, uint64* __restrict__ cntmat,
        uint64* __restrict__ flags,
        const float* __restrict__ Wl, const float* __restrict__ Ws,
        const float* __restrict__ bl, const float* __restrict__ bs,
        unsigned short* __restrict__ WcF, float* __restrict__ biasc,
        uint32* __restrict__ bpair) {
    const int t = threadIdx.x;
    const int b = blockIdx.x;              // bucket id (scan) == chunk id (scatter)
    const int gidx = b * 256 + t;
    if (gidx < 4096) {
        int lane = gidx & 63, f2 = gidx >> 6;
        int ks = f2 & 7, nn = (f2 >> 3) & 3, ch = f2 >> 5;
        int j = ch * 64 + nn * 16 + (lane & 15);
        int kb = ks * 32 + (lane >> 4) * 8;
        const float* srcp = (kb < D) ? (Wl + (size_t)j * D + kb)
                                     : (Ws + (size_t)j * D + (kb - D));
        const float4 v0 = *reinterpret_cast<const float4*>(srcp);
        const float4 v1 = *reinterpret_cast<const float4*>(srcp + 4);
        uint4 w;
        w.x = f2bf(v0.x) | (f2bf(v0.y) << 16);
        w.y = f2bf(v0.z) | (f2bf(v0.w) << 16);
        w.z = f2bf(v1.x) | (f2bf(v1.y) << 16);
        w.w = f2bf(v1.z) | (f2bf(v1.w) << 16);
        *reinterpret_cast<uint4*>(WcF + (size_t)gidx * 8) = w;
    }
    if (gidx < D) biasc[gidx] = bl[gidx] + bs[gidx];

    __shared__ uint32 s[256];
    __shared__ uint32 r2[256];
    __shared__ uint32 c[NB];
    __shared__ uint32 bb[NB];

    // ---- scan phase: bucket-row b ----
    uint32 v = 0;
    if (t < NCH) v = (uint32)cntmat[(size_t)b * NCH + t];
    s[t] = v;
    __syncthreads();
    for (int d = 1; d < 256; d <<= 1) {
        uint32 add = (t >= d) ? s[t - d] : 0u;
        __syncthreads();
        s[t] += add;
        __syncthreads();
    }
    const uint32 incl = s[t];
    const uint32 total = s[255];
    if (t == 0) atomicExch(&flags[b], (1ULL << 32) | (uint64)total);
    uint32 agg = 0;
    if (t < b) {                                       // b <= 195 < 256
        uint64 fv;
        do { fv = atomicAdd(&flags[t], 0ULL); } while ((fv >> 32) == 0ULL);
        agg = (uint32)fv;
    }
    r2[t] = agg;
    __syncthreads();
    for (int d2 = 128; d2 > 0; d2 >>= 1) {
        if (t < d2) r2[t] += r2[t + d2];
        __syncthreads();
    }
    const uint32 blockbase = r2[0];
    if (t < NCH)
        atomicExch(&cntmat[(size_t)b * NCH + t],
                   (1ULL << 32) | (uint64)(blockbase + incl - v));   // flagged base

    // ---- scatter phase: chunk b ----
    if (t < NB) {
        uint64 e;
        do { e = atomicAdd(&cntmat[(size_t)t * NCH + b], 0ULL); } while ((e >> 32) == 0ULL);
        bb[t] = (uint32)e;
        c[t] = 0u;
    }
    __syncthreads();
    const int e0 = b * CE;
    const int e1 = (e0 + CE < N_EDGES) ? e0 + CE : N_EDGES;
    for (int e = e0 + t; e < e1; e += 256) {
        uint32 src = (uint32)edges[e];
        uint32 tgt = (uint32)edges[N_EDGES + e];
        uint32 bkt = tgt >> 9;
        uint32 r = atomicAdd(&c[bkt], 1u);             // LDS atomic
        bpair[bb[bkt] + r] = ((tgt & 511u) << 17) | src;   // packed: lt | src
    }
}

// ---------------------------------------------------------------------------
// K4: one block per bucket. LDS 512-counter histogram -> local exclusive
// scan -> off[] (+ sentinel) and sorted_src (L2-local windows).
// ---------------------------------------------------------------------------
__global__ __launch_bounds__(256) void k4_csr(
        const uint32* __restrict__ bpair, const uint64* __restrict__ base,
        uint32* __restrict__ off, uint32* __restrict__ sorted_src) {
    __shared__ uint32 h[BWID];
    __shared__ uint32 h2[BWID];
    __shared__ uint32 pr[256];
    const int t = threadIdx.x;
    const int b = blockIdx.x;
    const uint32 start = (uint32)base[(size_t)b * NCH];
    const uint32 end = (b == NB - 1) ? N_EDGES : (uint32)base[(size_t)(b + 1) * NCH];
    for (int i = t; i < BWID; i += 256) { h[i] = 0u; h2[i] = 0u; }
    __syncthreads();
    // phase A: per-node counts
    for (uint32 e = start + t; e < end; e += 256) {
        atomicAdd(&h[bpair[e] >> 17], 1u);             // LDS atomic
    }
    __syncthreads();
    // phase B: exclusive scan of h[512] via 256-thread pair scan
    const uint32 e0c = h[2 * t];
    const uint32 e1c = h[2 * t + 1];
    pr[t] = e0c + e1c;
    __syncthreads();
    for (int d = 1; d < 256; d <<= 1) {
        uint32 add = (t >= d) ? pr[t - d] : 0u;
        __syncthreads();
        pr[t] += add;
        __syncthreads();
    }
    const uint32 exb = (t > 0) ? pr[t - 1] : 0u;
    const int node0 = b * BWID + 2 * t;
    if (node0 < N_NODES) off[node0] = start + exb;
    if (node0 + 1 < N_NODES) off[node0 + 1] = start + exb + e0c;
    if (b == NB - 1 && t == 0) off[N_NODES] = N_EDGES;  // sentinel
    h[2 * t] = exb;                                     // counts -> local offs
    h[2 * t + 1] = exb + e0c;
    __syncthreads();
    // phase C: place sources
    for (uint32 e = start + t; e < end; e += 256) {
        uint32 pq = bpair[e];
        uint32 lt = pq >> 17;
        uint32 r = atomicAdd(&h2[lt], 1u);              // LDS atomic
        sorted_src[start + h[lt] + r] = pq & 0x1FFFFu;
    }
}

// ---------------------------------------------------------------------------
// Gather-mean: 2 nodes per wave, lane = {g:node, sub:edge parity, cl:16B
// chunk}. Main loop: 16 edges/node/iter (8 loads in flight). Tail: ONE
// fully-predicated 16-slot batch (clamped index + cndmask) -> a single
// latency round for 99.98% of nodes.
// ---------------------------------------------------------------------------
__global__ __launch_bounds__(256) void k_gather(
        const unsigned short* __restrict__ AbufC,
        unsigned short* __restrict__ Abuf,
        const uint32* __restrict__ off,
        const uint32* __restrict__ sorted_src) {
    const int wave = threadIdx.x >> 6;
    const int lane = threadIdx.x & 63;
    const int sub  = (lane >> 4) & 1;      // edge parity
    const int cl   = lane & 15;            // 16B column chunk
    const int node = blockIdx.x * 8 + wave * 2 + (lane >> 5);
    const uint32 o = off[node];
    const uint32 d = off[node + 1] - o;
    const uint32* __restrict__ src = sorted_src + o;

#define LD(s) (*reinterpret_cast<const uint4*>(AbufC + (size_t)(s) * 256 + D + cl * 8))
#define ACC(a, u) { a[0] += bflo(u.x); a[1] += bfhi(u.x); a[2] += bflo(u.y); a[3] += bfhi(u.y); \
                    a[4] += bflo(u.z); a[5] += bfhi(u.z); a[6] += bflo(u.w); a[7] += bfhi(u.w); }

    float aA[8] = {0.f,0.f,0.f,0.f,0.f,0.f,0.f,0.f};
    float aB[8] = {0.f,0.f,0.f,0.f,0.f,0.f,0.f,0.f};
    uint32 j = 0;
    for (; j + 16 <= d; j += 16) {
        uint32 s0 = src[j +  0 + sub];
        uint32 s1 = src[j +  2 + sub];
        uint32 s2 = src[j +  4 + sub];
        uint32 s3 = src[j +  6 + sub];
        uint32 s4 = src[j +  8 + sub];
        uint32 s5 = src[j + 10 + sub];
        uint32 s6 = src[j + 12 + sub];
        uint32 s7 = src[j + 14 + sub];
        uint4 u0 = LD(s0); uint4 u1 = LD(s1); uint4 u2 = LD(s2); uint4 u3 = LD(s3);
        uint4 u4 = LD(s4); uint4 u5 = LD(s5); uint4 u6 = LD(s6); uint4 u7 = LD(s7);
        ACC(aA, u0); ACC(aA, u1); ACC(aB, u2); ACC(aB, u3);
        ACC(aA, u4); ACC(aA, u5); ACC(aB, u6); ACC(aB, u7);
    }
    if (j < d) {                           // <16 edges left: one predicated round
        const uint32 dm1 = d - 1;
        uint32 i0 = j +  0 + sub, i1 = j +  2 + sub, i2 = j +  4 + sub, i3 = j +  6 + sub;
        uint32 i4 = j +  8 + sub, i5 = j + 10 + sub, i6 = j + 12 + sub, i7 = j + 14 + sub;
        uint32 s0 = src[i0 < dm1 ? i0 : dm1];
        uint32 s1 = src[i1 < dm1 ? i1 : dm1];
        uint32 s2 = src[i2 < dm1 ? i2 : dm1];
        uint32 s3 = src[i3 < dm1 ? i3 : dm1];
        uint32 s4 = src[i4 < dm1 ? i4 : dm1];
        uint32 s5 = src[i5 < dm1 ? i5 : dm1];
        uint32 s6 = src[i6 < dm1 ? i6 : dm1];
        uint32 s7 = src[i7 < dm1 ? i7 : dm1];
        uint4 u0 = LD(s0); uint4 u1 = LD(s1); uint4 u2 = LD(s2); uint4 u3 = LD(s3);
        uint4 u4 = LD(s4); uint4 u5 = LD(s5); uint4 u6 = LD(s6); uint4 u7 = LD(s7);
        if (i0 >= d) { u0.x = 0u; u0.y = 0u; u0.z = 0u; u0.w = 0u; }
        if (i1 >= d) { u1.x = 0u; u1.y = 0u; u1.z = 0u; u1.w = 0u; }
        if (i2 >= d) { u2.x = 0u; u2.y = 0u; u2.z = 0u; u2.w = 0u; }
        if (i3 >= d) { u3.x = 0u; u3.y = 0u; u3.z = 0u; u3.w = 0u; }
        if (i4 >= d) { u4.x = 0u; u4.y = 0u; u4.z = 0u; u4.w = 0u; }
        if (i5 >= d) { u5.x = 0u; u5.y = 0u; u5.z = 0u; u5.w = 0u; }
        if (i6 >= d) { u6.x = 0u; u6.y = 0u; u6.z = 0u; u6.w = 0u; }
        if (i7 >= d) { u7.x = 0u; u7.y = 0u; u7.z = 0u; u7.w = 0u; }
        ACC(aA, u0); ACC(aA, u1); ACC(aB, u2); ACC(aB, u3);
        ACC(aA, u4); ACC(aA, u5); ACC(aB, u6); ACC(aB, u7);
    }
#undef LD
#undef ACC
#pragma unroll
    for (int r = 0; r < 8; ++r) {
        aA[r] += aB[r];
        aA[r] += __shfl_xor(aA[r], 16);    // sub0 + sub1 within the node group
    }
    if (sub == 0) {
        const float inv = 1.0f / (float)(d > 0u ? d : 1u);
        uint4 w;
        w.x = f2bf(aA[0] * inv) | (f2bf(aA[1] * inv) << 16);
        w.y = f2bf(aA[2] * inv) | (f2bf(aA[3] * inv) << 16);
        w.z = f2bf(aA[4] * inv) | (f2bf(aA[5] * inv) << 16);
        w.w = f2bf(aA[6] * inv) | (f2bf(aA[7] * inv) << 16);
        *reinterpret_cast<uint4*>(Abuf + (size_t)node * 256 + cl * 8) = w;
    }
}

// ---------------------------------------------------------------------------
// MFMA GEMM: block = 64 rows x 64 cols (colhalf ch = blockIdx&1), 4 waves of
// 16 rows each. B pre-fragmented in LDS (32 KB): conflict-free ds_read_b128.
// ---------------------------------------------------------------------------
__global__ __launch_bounds__(256) void sage_mfma(
        const unsigned short* __restrict__ Abuf,
        const unsigned short* __restrict__ WcF,
        const float* __restrict__ biasc,
        float* __restrict__ out) {
    __shared__ unsigned short WcL[16384];       // 32 KB = 32 frags x 1 KB
    const int tid = threadIdx.x;
    const int rb = blockIdx.x >> 1;
    const int ch = blockIdx.x & 1;

    const unsigned short* wsrc = WcF + (size_t)ch * 16384;
#pragma unroll
    for (int i = 0; i < 8; ++i) {
        const int o = (i * 256 + tid) * 8;
        *reinterpret_cast<short8*>(&WcL[o]) = *reinterpret_cast<const short8*>(wsrc + o);
    }
    __syncthreads();

    const int wave = tid >> 6;
    const int lane = tid & 63;
    const int lr = lane & 15;
    const int lk = (lane >> 4) * 8;
    const long long row0 = (long long)rb * 64 + wave * 16;

    f32x4 acc[4];
#pragma unroll
    for (int n = 0; n < 4; ++n) acc[n] = (f32x4){0.f, 0.f, 0.f, 0.f};

    const unsigned short* pa = Abuf + (row0 + lr) * 256 + lk;
#pragma unroll
    for (int ks = 0; ks < 8; ++ks) {
        short8 a = *reinterpret_cast<const short8*>(pa + ks * 32);
#pragma unroll
        for (int n = 0; n < 4; ++n) {
            short8 b = *reinterpret_cast<const short8*>(&WcL[((n * 8 + ks) * 64 + lane) * 8]);
            acc[n] = __builtin_amdgcn_mfma_f32_16x16x32_bf16(a, b, acc[n], 0, 0, 0);
        }
    }

    float bv[4];
#pragma unroll
    for (int n = 0; n < 4; ++n) bv[n] = biasc[ch * 64 + n * 16 + lr];

    const int rq = (lane >> 4) * 4;
#pragma unroll
    for (int r = 0; r < 4; ++r) {
        const long long row = row0 + rq + r;
        if (row < N_NODES) {
            float* orow = out + row * D + ch * 64;
#pragma unroll
            for (int n = 0; n < 4; ++n)
                orow[n * 16 + lr] = acc[n][r] + bv[n];
        }
    }
}

extern "C" void kernel_launch(void* const* d_in, const int* in_sizes, int n_in,
                              void* d_out, int out_size, void* d_ws, size_t ws_size,
                              hipStream_t stream) {
    const float* nf    = (const float*)d_in[0];
    const int*   edges = (const int*)d_in[1];
    const float* Wl    = (const float*)d_in[2];
    const float* bl    = (const float*)d_in[3];
    const float* Ws    = (const float*)d_in[4];
    const float* bs    = (const float*)d_in[5];
    float* out = (float*)d_out;

    // workspace layout
    char* p = (char*)d_ws;
    unsigned short* Abuf = (unsigned short*)p; p += (size_t)M_PAD * 256 * sizeof(unsigned short);
    uint64* cntmat     = (uint64*)p; p += (size_t)(NB * NCH + 16) * sizeof(uint64);
    uint32* bpair      = (uint32*)p; p += (size_t)N_EDGES * sizeof(uint32);
    uint32* sorted_src = (uint32*)p; p += (size_t)N_EDGES * sizeof(uint32);
    uint32* off        = (uint32*)p; p += (size_t)(N_NODES + 8) * sizeof(uint32);
    uint64* flags      = (uint64*)p; p += 2048;
    unsigned short* WcF = (unsigned short*)p; p += (size_t)D * 256 * sizeof(unsigned short);
    float* biasc       = (float*)p;

    k1_convert_count<<<1024, 256, 0, stream>>>(nf, Abuf, edges, cntmat, flags);
    k23_scan_bucket<<<NB, 256, 0, stream>>>(edges, cntmat, flags, Wl, Ws, bl, bs,
                                            WcF, biasc, bpair);
    k4_csr<<<NB, 256, 0, stream>>>(bpair, cntmat, off, sorted_src);
    k_gather<<<N_NODES / 8, 256, 0, stream>>>(Abuf, Abuf, off, sorted_src);
    sage_mfma<<<(M_PAD / 64) * 2, 256, 0, stream>>>(Abuf, WcF, biasc, out);
}

// Round 13
// 95.644 us; speedup vs baseline: 1.0540x; 1.0540x over previous
//
#include <hip/hip_runtime.h>

#define N_NODES 100000
#define N_EDGES 600000
#define D 128
#define M_PAD 100096            // allocation pad for AbufN rows

#define NB   196                // buckets = tgt >> 9
#define BWID 512                // nodes per bucket
#define NCH  196                // edge chunks
#define CE   3062               // edges per chunk (last: 2910)
#define SCAN_N (NB * NCH)       // 38416
#define SCAN_BLK 151            // ceil(SCAN_N / 256)

typedef unsigned int uint32;
typedef unsigned long long uint64;
typedef __attribute__((ext_vector_type(8))) short short8;
typedef __attribute__((ext_vector_type(4))) float f32x4;

__device__ __forceinline__ uint32 f2bf(float x) {          // RNE f32 -> bf16
    uint32 u = __float_as_uint(x);
    return (u + 0x7FFFu + ((u >> 16) & 1u)) >> 16;
}
__device__ __forceinline__ float bflo(uint32 u) { return __uint_as_float(u << 16); }
__device__ __forceinline__ float bfhi(uint32 u) { return __uint_as_float(u & 0xFFFF0000u); }

// ---------------------------------------------------------------------------
// K1: convert nf -> bf16 compact AbufN[r][128] (grid-stride, 1024 blocks);
// blocks 0..195 also count their edge-chunk's bucket histogram in LDS.
// Block 1023 zeroes the scan flags.
// ---------------------------------------------------------------------------
__global__ __launch_bounds__(256) void k1_convert_count(
        const float* __restrict__ nf, unsigned short* __restrict__ AbufN,
        const int* __restrict__ edges, uint32* __restrict__ cntmat,
        uint64* __restrict__ flags) {
    __shared__ uint32 c[NB];
    const int tid = threadIdx.x;
    const int bid = blockIdx.x;

    if (bid == 1023 && tid < SCAN_BLK) flags[tid] = 0ULL;

    for (int idx = bid * 256 + tid; idx < N_NODES * 16; idx += 1024 * 256) {
        int r = idx >> 4;
        int ccol = (idx & 15) * 8;
        const float4 v0 = *reinterpret_cast<const float4*>(nf + (size_t)r * D + ccol);
        const float4 v1 = *reinterpret_cast<const float4*>(nf + (size_t)r * D + ccol + 4);
        uint4 w;
        w.x = f2bf(v0.x) | (f2bf(v0.y) << 16);
        w.y = f2bf(v0.z) | (f2bf(v0.w) << 16);
        w.z = f2bf(v1.x) | (f2bf(v1.y) << 16);
        w.w = f2bf(v1.z) | (f2bf(v1.w) << 16);
        *reinterpret_cast<uint4*>(AbufN + (size_t)r * 128 + ccol) = w;
    }

    if (bid < NCH) {
        for (int i = tid; i < NB; i += 256) c[i] = 0u;
        __syncthreads();
        const int e0 = bid * CE;
        const int e1 = (e0 + CE < N_EDGES) ? e0 + CE : N_EDGES;
        for (int e = e0 + tid; e < e1; e += 256) {
            int tgt = edges[N_EDGES + e];
            atomicAdd(&c[tgt >> 9], 1u);               // LDS atomic
        }
        __syncthreads();
        for (int i = tid; i < NB; i += 256)
            cntmat[(size_t)i * NCH + bid] = c[i];      // bucket-major
    }
}

// ---------------------------------------------------------------------------
// K2: publish/poll exclusive scan over cntmat (38416 elems, 151 blocks),
// in-place counts -> bases. Idle width does W-prep + bias fuse.
// ---------------------------------------------------------------------------
__global__ __launch_bounds__(256) void k2_scan(
        uint32* __restrict__ cntmat, uint64* __restrict__ flags,
        const float* __restrict__ Wl, const float* __restrict__ Ws,
        const float* __restrict__ bl, const float* __restrict__ bs,
        unsigned short* __restrict__ WcF, float* __restrict__ biasc) {
    const int gidx = blockIdx.x * 256 + threadIdx.x;
    if (gidx < 4096) {
        int lane = gidx & 63, f2 = gidx >> 6;
        int ks = f2 & 7, nn = (f2 >> 3) & 3, ch = f2 >> 5;
        int j = ch * 64 + nn * 16 + (lane & 15);
        int kb = ks * 32 + (lane >> 4) * 8;
        const float* srcp = (kb < D) ? (Wl + (size_t)j * D + kb)
                                     : (Ws + (size_t)j * D + (kb - D));
        const float4 v0 = *reinterpret_cast<const float4*>(srcp);
        const float4 v1 = *reinterpret_cast<const float4*>(srcp + 4);
        uint4 w;
        w.x = f2bf(v0.x) | (f2bf(v0.y) << 16);
        w.y = f2bf(v0.z) | (f2bf(v0.w) << 16);
        w.z = f2bf(v1.x) | (f2bf(v1.y) << 16);
        w.w = f2bf(v1.z) | (f2bf(v1.w) << 16);
        *reinterpret_cast<uint4*>(WcF + (size_t)gidx * 8) = w;
    }
    if (gidx < D) biasc[gidx] = bl[gidx] + bs[gidx];

    __shared__ uint32 s[256];
    __shared__ uint32 r2[256];
    const int t = threadIdx.x;
    const int b = blockIdx.x;
    const int i = b * 256 + t;
    const uint32 v = (i < SCAN_N) ? cntmat[i] : 0u;
    s[t] = v;
    __syncthreads();
    for (int d = 1; d < 256; d <<= 1) {
        uint32 add = (t >= d) ? s[t - d] : 0u;
        __syncthreads();
        s[t] += add;
        __syncthreads();
    }
    const uint32 incl = s[t];
    const uint32 total = s[255];
    if (t == 0) atomicExch(&flags[b], (1ULL << 32) | (uint64)total);
    uint32 agg = 0;
    if (t < b) {                                       // b <= 150 < 256
        uint64 fv;
        do { fv = atomicAdd(&flags[t], 0ULL); } while ((fv >> 32) == 0ULL);
        agg = (uint32)fv;
    }
    r2[t] = agg;
    __syncthreads();
    for (int d2 = 128; d2 > 0; d2 >>= 1) {
        if (t < d2) r2[t] += r2[t + d2];
        __syncthreads();
    }
    if (i < SCAN_N) cntmat[i] = r2[0] + incl - v;      // exclusive base, in place
}

// ---------------------------------------------------------------------------
// K3: scatter edges into bucket-grouped pair array. Rank via LDS atomic
// return + disjoint (bucket,chunk) base ranges -> no global atomics.
// ---------------------------------------------------------------------------
__global__ __launch_bounds__(256) void k3_bucket(
        const int* __restrict__ edges, const uint32* __restrict__ base,
        uint32* __restrict__ bpair) {
    __shared__ uint32 c[NB];
    __shared__ uint32 bb[NB];
    const int t = threadIdx.x;
    const int cid = blockIdx.x;
    for (int i = t; i < NB; i += 256) {
        c[i] = 0u;
        bb[i] = base[(size_t)i * NCH + cid];
    }
    __syncthreads();
    const int e0 = cid * CE;
    const int e1 = (e0 + CE < N_EDGES) ? e0 + CE : N_EDGES;
    for (int e = e0 + t; e < e1; e += 256) {
        uint32 src = (uint32)edges[e];
        uint32 tgt = (uint32)edges[N_EDGES + e];
        uint32 bkt = tgt >> 9;
        uint32 r = atomicAdd(&c[bkt], 1u);             // LDS atomic
        uint32 pos = bb[bkt] + r;
        *reinterpret_cast<uint2*>(&bpair[2 * (size_t)pos]) = make_uint2(src, tgt);
    }
}

// ---------------------------------------------------------------------------
// K4: one block per bucket. LDS 512-counter histogram -> local exclusive
// scan -> off[] (+ sentinel) and sorted_src (L2-local windows).
// ---------------------------------------------------------------------------
__global__ __launch_bounds__(256) void k4_csr(
        const uint32* __restrict__ bpair, const uint32* __restrict__ base,
        uint32* __restrict__ off, uint32* __restrict__ sorted_src) {
    __shared__ uint32 h[BWID];
    __shared__ uint32 h2[BWID];
    __shared__ uint32 pr[256];
    const int t = threadIdx.x;
    const int b = blockIdx.x;
    const uint32 start = base[(size_t)b * NCH];
    const uint32 end = (b == NB - 1) ? N_EDGES : base[(size_t)(b + 1) * NCH];
    for (int i = t; i < BWID; i += 256) { h[i] = 0u; h2[i] = 0u; }
    __syncthreads();
    for (uint32 e = start + t; e < end; e += 256) {
        uint32 tgt = bpair[2 * (size_t)e + 1];
        atomicAdd(&h[tgt & (BWID - 1)], 1u);           // LDS atomic
    }
    __syncthreads();
    const uint32 e0c = h[2 * t];
    const uint32 e1c = h[2 * t + 1];
    pr[t] = e0c + e1c;
    __syncthreads();
    for (int d = 1; d < 256; d <<= 1) {
        uint32 add = (t >= d) ? pr[t - d] : 0u;
        __syncthreads();
        pr[t] += add;
        __syncthreads();
    }
    const uint32 exb = (t > 0) ? pr[t - 1] : 0u;
    const int node0 = b * BWID + 2 * t;
    if (node0 < N_NODES) off[node0] = start + exb;
    if (node0 + 1 < N_NODES) off[node0 + 1] = start + exb + e0c;
    if (b == NB - 1 && t == 0) off[N_NODES] = N_EDGES;  // sentinel
    h[2 * t] = exb;
    h[2 * t + 1] = exb + e0c;
    __syncthreads();
    for (uint32 e = start + t; e < end; e += 256) {
        uint2 pq = *reinterpret_cast<const uint2*>(&bpair[2 * (size_t)e]);
        uint32 lt = pq.y & (BWID - 1);
        uint32 r = atomicAdd(&h2[lt], 1u);              // LDS atomic
        sorted_src[start + h[lt] + r] = pq.x;
    }
}

// ---------------------------------------------------------------------------
// K5 fused gather + MFMA GEMM. Block = 64 rows x 128 cols, 512 threads.
// Phase 1: stage W frags (64 KB LDS); gather block's 64 nodes, mean -> LDS
//          (16 KB, chunk ^= row&7 swizzle), never touching global.
// Phase 2: MFMA; A ks0-3 from LDS-mean, ks4-7 from compact AbufN (global).
// 80 KB LDS -> 2 blocks/CU; gather-phase blocks overlap MFMA-phase blocks.
// ---------------------------------------------------------------------------
__global__ __launch_bounds__(512) void k_fused(
        const unsigned short* __restrict__ AbufN,
        const uint32* __restrict__ off,
        const uint32* __restrict__ sorted_src,
        const unsigned short* __restrict__ WcF,
        const float* __restrict__ biasc,
        float* __restrict__ out) {
    __shared__ unsigned short WcL[32768];       // 64 KB: 4096 x 16 B frag chunks
    __shared__ unsigned short Am[8192];         // 16 KB: 64 rows x 128 cols bf16
    const int tid = threadIdx.x;
    const int wave = tid >> 6;                  // 0..7
    const int lane = tid & 63;
    const int row0 = blockIdx.x * 64;

    // stage all W fragments (linear copy)
#pragma unroll
    for (int i = 0; i < 8; ++i) {
        const int o = (i * 512 + tid) * 8;
        *reinterpret_cast<short8*>(&WcL[o]) = *reinterpret_cast<const short8*>(WcF + o);
    }

    // ---- gather phase: 4 node-pairs per wave ----
    const int sub = (lane >> 4) & 1;            // edge parity
    const int cl  = lane & 15;                  // 16B column chunk
    const int g   = lane >> 5;                  // node within pair

#define LD(s) (*reinterpret_cast<const uint4*>(AbufN + (size_t)(s) * 128 + cl * 8))
#define ACC(a, u) { a[0] += bflo(u.x); a[1] += bfhi(u.x); a[2] += bflo(u.y); a[3] += bfhi(u.y); \
                    a[4] += bflo(u.z); a[5] += bfhi(u.z); a[6] += bflo(u.w); a[7] += bfhi(u.w); }

    for (int pr = 0; pr < 4; ++pr) {
        const int nl = wave * 8 + pr * 2 + g;   // local row 0..63
        const int node = row0 + nl;
        float aA[8] = {0.f,0.f,0.f,0.f,0.f,0.f,0.f,0.f};
        float aB[8] = {0.f,0.f,0.f,0.f,0.f,0.f,0.f,0.f};
        uint32 d = 0;
        if (node < N_NODES) {
            const uint32 o = off[node];
            d = off[node + 1] - o;
            const uint32* __restrict__ src = sorted_src + o;
            uint32 j = 0;
            for (; j + 8 <= d; j += 8) {
                uint32 s0 = src[j + 0 + sub];
                uint32 s1 = src[j + 2 + sub];
                uint32 s2 = src[j + 4 + sub];
                uint32 s3 = src[j + 6 + sub];
                uint4 u0 = LD(s0); uint4 u1 = LD(s1); uint4 u2 = LD(s2); uint4 u3 = LD(s3);
                ACC(aA, u0); ACC(aA, u1); ACC(aB, u2); ACC(aB, u3);
            }
            if (j < d) {                        // <8 left: one predicated round
                const uint32 dm1 = d - 1;
                uint32 i0 = j + 0 + sub, i1 = j + 2 + sub, i2 = j + 4 + sub, i3 = j + 6 + sub;
                uint32 s0 = src[i0 < dm1 ? i0 : dm1];
                uint32 s1 = src[i1 < dm1 ? i1 : dm1];
                uint32 s2 = src[i2 < dm1 ? i2 : dm1];
                uint32 s3 = src[i3 < dm1 ? i3 : dm1];
                uint4 u0 = LD(s0); uint4 u1 = LD(s1); uint4 u2 = LD(s2); uint4 u3 = LD(s3);
                if (i0 >= d) { u0.x = 0u; u0.y = 0u; u0.z = 0u; u0.w = 0u; }
                if (i1 >= d) { u1.x = 0u; u1.y = 0u; u1.z = 0u; u1.w = 0u; }
                if (i2 >= d) { u2.x = 0u; u2.y = 0u; u2.z = 0u; u2.w = 0u; }
                if (i3 >= d) { u3.x = 0u; u3.y = 0u; u3.z = 0u; u3.w = 0u; }
                ACC(aA, u0); ACC(aA, u1); ACC(aB, u2); ACC(aB, u3);
            }
        }
#pragma unroll
        for (int r = 0; r < 8; ++r) {
            aA[r] += aB[r];
            aA[r] += __shfl_xor(aA[r], 16);     // sub0 + sub1
        }
        if (sub == 0) {
            const float inv = 1.0f / (float)(d > 0u ? d : 1u);
            uint4 w;
            w.x = f2bf(aA[0] * inv) | (f2bf(aA[1] * inv) << 16);
            w.y = f2bf(aA[2] * inv) | (f2bf(aA[3] * inv) << 16);
            w.z = f2bf(aA[4] * inv) | (f2bf(aA[5] * inv) << 16);
            w.w = f2bf(aA[6] * inv) | (f2bf(aA[7] * inv) << 16);
            // swizzled LDS write: chunk ^= row&7 (bank-conflict-free frag reads)
            *reinterpret_cast<uint4*>(&Am[nl * 128 + ((cl ^ (nl & 7)) * 8)]) = w;
        }
    }
#undef LD
#undef ACC
    __syncthreads();

    // ---- GEMM phase: wave = 16 rows x 64 cols (rg = wave>>1, chh = wave&1) ----
    const int rg  = wave >> 1;
    const int chh = wave & 1;
    const int lr  = lane & 15;
    const int lkq = lane >> 4;                  // 0..3
    const int lk  = lkq * 8;
    const int arow = rg * 16 + lr;              // local row

    f32x4 acc[4];
#pragma unroll
    for (int n = 0; n < 4; ++n) acc[n] = (f32x4){0.f, 0.f, 0.f, 0.f};

    // mean half (ks 0..3) from LDS, swizzled
#pragma unroll
    for (int ks = 0; ks < 4; ++ks) {
        const int c0 = lkq + ks * 4;
        short8 a = *reinterpret_cast<const short8*>(
            &Am[arow * 128 + ((c0 ^ (arow & 7)) * 8)]);
#pragma unroll
        for (int n = 0; n < 4; ++n) {
            short8 b = *reinterpret_cast<const short8*>(
                &WcL[((chh * 32 + n * 8 + ks) * 64 + lane) * 8]);
            acc[n] = __builtin_amdgcn_mfma_f32_16x16x32_bf16(a, b, acc[n], 0, 0, 0);
        }
    }
    // nf half (ks 4..7) from global compact AbufN
    const unsigned short* pa = AbufN + (size_t)(row0 + arow) * 128 + lk;
#pragma unroll
    for (int ks = 4; ks < 8; ++ks) {
        short8 a = *reinterpret_cast<const short8*>(pa + (ks - 4) * 32);
#pragma unroll
        for (int n = 0; n < 4; ++n) {
            short8 b = *reinterpret_cast<const short8*>(
                &WcL[((chh * 32 + n * 8 + ks) * 64 + lane) * 8]);
            acc[n] = __builtin_amdgcn_mfma_f32_16x16x32_bf16(a, b, acc[n], 0, 0, 0);
        }
    }

    // epilogue (C/D: col = lane&15, row = (lane>>4)*4 + reg)
    float bv[4];
#pragma unroll
    for (int n = 0; n < 4; ++n) bv[n] = biasc[chh * 64 + n * 16 + lr];

    const int rq = lkq * 4;
#pragma unroll
    for (int r = 0; r < 4; ++r) {
        const int row = row0 + rg * 16 + rq + r;
        if (row < N_NODES) {
            float* orow = out + (size_t)row * D + chh * 64;
#pragma unroll
            for (int n = 0; n < 4; ++n)
                orow[n * 16 + lr] = acc[n][r] + bv[n];
        }
    }
}

extern "C" void kernel_launch(void* const* d_in, const int* in_sizes, int n_in,
                              void* d_out, int out_size, void* d_ws, size_t ws_size,
                              hipStream_t stream) {
    const float* nf    = (const float*)d_in[0];
    const int*   edges = (const int*)d_in[1];
    const float* Wl    = (const float*)d_in[2];
    const float* bl    = (const float*)d_in[3];
    const float* Ws    = (const float*)d_in[4];
    const float* bs    = (const float*)d_in[5];
    float* out = (float*)d_out;

    // workspace layout
    char* p = (char*)d_ws;
    unsigned short* AbufN = (unsigned short*)p; p += (size_t)M_PAD * 128 * sizeof(unsigned short);
    uint32* cntmat     = (uint32*)p; p += (size_t)(SCAN_N + 64) * sizeof(uint32);
    uint32* bpair      = (uint32*)p; p += (size_t)2 * N_EDGES * sizeof(uint32);
    uint32* sorted_src = (uint32*)p; p += (size_t)N_EDGES * sizeof(uint32);
    uint32* off        = (uint32*)p; p += (size_t)(N_NODES + 8) * sizeof(uint32);
    uint64* flags      = (uint64*)p; p += 2048;
    unsigned short* WcF = (unsigned short*)p; p += (size_t)D * 256 * sizeof(unsigned short);
    float* biasc       = (float*)p;

    k1_convert_count<<<1024, 256, 0, stream>>>(nf, AbufN, edges, cntmat, flags);
    k2_scan<<<SCAN_BLK, 256, 0, stream>>>(cntmat, flags, Wl, Ws, bl, bs, WcF, biasc);
    k3_bucket<<<NCH, 256, 0, stream>>>(edges, cntmat, bpair);
    k4_csr<<<NB, 256, 0, stream>>>(bpair, cntmat, off, sorted_src);
    k_fused<<<(N_NODES + 63) / 64, 512, 0, stream>>>(AbufN, off, sorted_src, WcF, biasc, out);
}

// Round 14
// 87.546 us; speedup vs baseline: 1.1515x; 1.0925x over previous
//
#include <hip/hip_runtime.h>

#define N_NODES 100000
#define N_EDGES 600000
#define D 128
#define M_PAD 100096            // allocation pad for AbufN rows

#define NB   196                // buckets = tgt >> 9
#define BWID 512                // nodes per bucket
#define NCH  196                // edge chunks
#define CE   3062               // edges per chunk (last: 2910)
#define SCAN_N (NB * NCH)       // 38416
#define SCAN_BLK 151            // ceil(SCAN_N / 256)

typedef unsigned int uint32;
typedef unsigned long long uint64;
typedef __attribute__((ext_vector_type(8))) short short8;
typedef __attribute__((ext_vector_type(4))) float f32x4;

__device__ __forceinline__ uint32 f2bf(float x) {          // RNE f32 -> bf16
    uint32 u = __float_as_uint(x);
    return (u + 0x7FFFu + ((u >> 16) & 1u)) >> 16;
}
__device__ __forceinline__ float bflo(uint32 u) { return __uint_as_float(u << 16); }
__device__ __forceinline__ float bfhi(uint32 u) { return __uint_as_float(u & 0xFFFF0000u); }

// ---------------------------------------------------------------------------
// K1: convert nf -> bf16 compact AbufN[r][128] (grid-stride, 1024 blocks);
// blocks 0..195 also count their edge-chunk's bucket histogram in LDS.
// Block 1023 zeroes the scan flags.
// ---------------------------------------------------------------------------
__global__ __launch_bounds__(256) void k1_convert_count(
        const float* __restrict__ nf, unsigned short* __restrict__ AbufN,
        const int* __restrict__ edges, uint32* __restrict__ cntmat,
        uint64* __restrict__ flags) {
    __shared__ uint32 c[NB];
    const int tid = threadIdx.x;
    const int bid = blockIdx.x;

    if (bid == 1023 && tid < SCAN_BLK) flags[tid] = 0ULL;

    for (int idx = bid * 256 + tid; idx < N_NODES * 16; idx += 1024 * 256) {
        int r = idx >> 4;
        int ccol = (idx & 15) * 8;
        const float4 v0 = *reinterpret_cast<const float4*>(nf + (size_t)r * D + ccol);
        const float4 v1 = *reinterpret_cast<const float4*>(nf + (size_t)r * D + ccol + 4);
        uint4 w;
        w.x = f2bf(v0.x) | (f2bf(v0.y) << 16);
        w.y = f2bf(v0.z) | (f2bf(v0.w) << 16);
        w.z = f2bf(v1.x) | (f2bf(v1.y) << 16);
        w.w = f2bf(v1.z) | (f2bf(v1.w) << 16);
        *reinterpret_cast<uint4*>(AbufN + (size_t)r * 128 + ccol) = w;
    }

    if (bid < NCH) {
        for (int i = tid; i < NB; i += 256) c[i] = 0u;
        __syncthreads();
        const int e0 = bid * CE;
        const int e1 = (e0 + CE < N_EDGES) ? e0 + CE : N_EDGES;
        for (int e = e0 + tid; e < e1; e += 256) {
            int tgt = edges[N_EDGES + e];
            atomicAdd(&c[tgt >> 9], 1u);               // LDS atomic
        }
        __syncthreads();
        for (int i = tid; i < NB; i += 256)
            cntmat[(size_t)i * NCH + bid] = c[i];      // bucket-major
    }
}

// ---------------------------------------------------------------------------
// K2: publish/poll exclusive scan over cntmat (38416 elems, 151 blocks),
// in-place counts -> bases. Idle width does W-prep + bias fuse.
// ---------------------------------------------------------------------------
__global__ __launch_bounds__(256) void k2_scan(
        uint32* __restrict__ cntmat, uint64* __restrict__ flags,
        const float* __restrict__ Wl, const float* __restrict__ Ws,
        const float* __restrict__ bl, const float* __restrict__ bs,
        unsigned short* __restrict__ WcF, float* __restrict__ biasc) {
    const int gidx = blockIdx.x * 256 + threadIdx.x;
    if (gidx < 4096) {
        int lane = gidx & 63, f2 = gidx >> 6;
        int ks = f2 & 7, nn = (f2 >> 3) & 3, ch = f2 >> 5;
        int j = ch * 64 + nn * 16 + (lane & 15);
        int kb = ks * 32 + (lane >> 4) * 8;
        const float* srcp = (kb < D) ? (Wl + (size_t)j * D + kb)
                                     : (Ws + (size_t)j * D + (kb - D));
        const float4 v0 = *reinterpret_cast<const float4*>(srcp);
        const float4 v1 = *reinterpret_cast<const float4*>(srcp + 4);
        uint4 w;
        w.x = f2bf(v0.x) | (f2bf(v0.y) << 16);
        w.y = f2bf(v0.z) | (f2bf(v0.w) << 16);
        w.z = f2bf(v1.x) | (f2bf(v1.y) << 16);
        w.w = f2bf(v1.z) | (f2bf(v1.w) << 16);
        *reinterpret_cast<uint4*>(WcF + (size_t)gidx * 8) = w;
    }
    if (gidx < D) biasc[gidx] = bl[gidx] + bs[gidx];

    __shared__ uint32 s[256];
    __shared__ uint32 r2[256];
    const int t = threadIdx.x;
    const int b = blockIdx.x;
    const int i = b * 256 + t;
    const uint32 v = (i < SCAN_N) ? cntmat[i] : 0u;
    s[t] = v;
    __syncthreads();
    for (int d = 1; d < 256; d <<= 1) {
        uint32 add = (t >= d) ? s[t - d] : 0u;
        __syncthreads();
        s[t] += add;
        __syncthreads();
    }
    const uint32 incl = s[t];
    const uint32 total = s[255];
    if (t == 0) atomicExch(&flags[b], (1ULL << 32) | (uint64)total);
    uint32 agg = 0;
    if (t < b) {                                       // b <= 150 < 256
        uint64 fv;
        do { fv = atomicAdd(&flags[t], 0ULL); } while ((fv >> 32) == 0ULL);
        agg = (uint32)fv;
    }
    r2[t] = agg;
    __syncthreads();
    for (int d2 = 128; d2 > 0; d2 >>= 1) {
        if (t < d2) r2[t] += r2[t + d2];
        __syncthreads();
    }
    if (i < SCAN_N) cntmat[i] = r2[0] + incl - v;      // exclusive base, in place
}

// ---------------------------------------------------------------------------
// K3: scatter edges into bucket-grouped PACKED array ((tgt&511)<<17 | src).
// Rank via LDS atomic return + disjoint (bucket,chunk) bases -> no g-atomics.
// ---------------------------------------------------------------------------
__global__ __launch_bounds__(256) void k3_bucket(
        const int* __restrict__ edges, const uint32* __restrict__ base,
        uint32* __restrict__ bpair) {
    __shared__ uint32 c[NB];
    __shared__ uint32 bb[NB];
    const int t = threadIdx.x;
    const int cid = blockIdx.x;
    for (int i = t; i < NB; i += 256) {
        c[i] = 0u;
        bb[i] = base[(size_t)i * NCH + cid];
    }
    __syncthreads();
    const int e0 = cid * CE;
    const int e1 = (e0 + CE < N_EDGES) ? e0 + CE : N_EDGES;
    for (int e = e0 + t; e < e1; e += 256) {
        uint32 src = (uint32)edges[e];
        uint32 tgt = (uint32)edges[N_EDGES + e];
        uint32 bkt = tgt >> 9;
        uint32 r = atomicAdd(&c[bkt], 1u);             // LDS atomic
        bpair[bb[bkt] + r] = ((tgt & 511u) << 17) | src;
    }
}

// ---------------------------------------------------------------------------
// K4: one block per bucket. LDS 512-counter histogram -> local exclusive
// scan -> off[] (+ sentinel) and sorted_src (L2-local windows).
// ---------------------------------------------------------------------------
__global__ __launch_bounds__(256) void k4_csr(
        const uint32* __restrict__ bpair, const uint32* __restrict__ base,
        uint32* __restrict__ off, uint32* __restrict__ sorted_src) {
    __shared__ uint32 h[BWID];
    __shared__ uint32 h2[BWID];
    __shared__ uint32 pr[256];
    const int t = threadIdx.x;
    const int b = blockIdx.x;
    const uint32 start = base[(size_t)b * NCH];
    const uint32 end = (b == NB - 1) ? N_EDGES : base[(size_t)(b + 1) * NCH];
    for (int i = t; i < BWID; i += 256) { h[i] = 0u; h2[i] = 0u; }
    __syncthreads();
    for (uint32 e = start + t; e < end; e += 256) {
        atomicAdd(&h[bpair[e] >> 17], 1u);             // LDS atomic
    }
    __syncthreads();
    const uint32 e0c = h[2 * t];
    const uint32 e1c = h[2 * t + 1];
    pr[t] = e0c + e1c;
    __syncthreads();
    for (int d = 1; d < 256; d <<= 1) {
        uint32 add = (t >= d) ? pr[t - d] : 0u;
        __syncthreads();
        pr[t] += add;
        __syncthreads();
    }
    const uint32 exb = (t > 0) ? pr[t - 1] : 0u;
    const int node0 = b * BWID + 2 * t;
    if (node0 < N_NODES) off[node0] = start + exb;
    if (node0 + 1 < N_NODES) off[node0 + 1] = start + exb + e0c;
    if (b == NB - 1 && t == 0) off[N_NODES] = N_EDGES;  // sentinel
    h[2 * t] = exb;
    h[2 * t + 1] = exb + e0c;
    __syncthreads();
    for (uint32 e = start + t; e < end; e += 256) {
        uint32 pq = bpair[e];
        uint32 lt = pq >> 17;
        uint32 r = atomicAdd(&h2[lt], 1u);              // LDS atomic
        sorted_src[start + h[lt] + r] = pq & 0x1FFFFu;
    }
}

// ---------------------------------------------------------------------------
// K5 fused gather + MFMA GEMM. Block = 64 rows x 128 cols, 512 threads.
// Gather phase restructured for cross-pair MLP: hoist all 4 pairs' off loads,
// all 16 first-round index loads; row loads in 2 groups of 8; rare d>8
// leftovers per pair. Mean -> LDS only (swizzled). Then MFMA from LDS + AbufN.
// ---------------------------------------------------------------------------
__global__ __launch_bounds__(512) void k_fused(
        const unsigned short* __restrict__ AbufN,
        const uint32* __restrict__ off,
        const uint32* __restrict__ sorted_src,
        const unsigned short* __restrict__ WcF,
        const float* __restrict__ biasc,
        float* __restrict__ out) {
    __shared__ unsigned short WcL[32768];       // 64 KB
    __shared__ unsigned short Am[8192];         // 16 KB: 64 x 128 bf16 (swizzled)
    const int tid = threadIdx.x;
    const int wave = tid >> 6;                  // 0..7
    const int lane = tid & 63;
    const int row0 = blockIdx.x * 64;

    // stage all W fragments (linear copy; overlaps with gather loads)
#pragma unroll
    for (int i = 0; i < 8; ++i) {
        const int o = (i * 512 + tid) * 8;
        *reinterpret_cast<short8*>(&WcL[o]) = *reinterpret_cast<const short8*>(WcF + o);
    }

    const int sub = (lane >> 4) & 1;            // edge parity
    const int cl  = lane & 15;                  // 16B column chunk
    const int g   = lane >> 5;                  // node within pair

#define LD(s) (*reinterpret_cast<const uint4*>(AbufN + (size_t)(s) * 128 + cl * 8))
#define ACC(a, u) { a[0] += bflo(u.x); a[1] += bfhi(u.x); a[2] += bflo(u.y); a[3] += bfhi(u.y); \
                    a[4] += bflo(u.z); a[5] += bfhi(u.z); a[6] += bflo(u.w); a[7] += bfhi(u.w); }

    // ---- hoisted off/deg loads: 4 pairs, 8 independent loads ----
    uint32 oo[4], dd[4];
#pragma unroll
    for (int pr2 = 0; pr2 < 4; ++pr2) {
        const int nl = wave * 8 + pr2 * 2 + g;
        const int node = row0 + nl;
        const int nn = (node < N_NODES) ? node : (N_NODES - 1);
        const uint32 o0 = off[nn];
        const uint32 o1 = off[nn + 1];
        oo[pr2] = o0;
        dd[pr2] = (node < N_NODES) ? (o1 - o0) : 0u;
    }
    // ---- hoisted first-round index loads: 16 independent ----
    uint32 sx[4][4];
#pragma unroll
    for (int pr2 = 0; pr2 < 4; ++pr2) {
        const uint32 d0 = dd[pr2];
        const uint32 dm = d0 ? d0 - 1u : 0u;
        const uint32* sp = sorted_src + oo[pr2];
#pragma unroll
        for (int k = 0; k < 4; ++k) {
            uint32 i = 2u * (uint32)k + (uint32)sub;
            sx[pr2][k] = sp[i < dm ? i : dm];
        }
    }
#pragma unroll
    for (int pr2 = 0; pr2 < 4; ++pr2)
#pragma unroll
        for (int k = 0; k < 4; ++k)
            if (2u * (uint32)k + (uint32)sub >= dd[pr2]) sx[pr2][k] = 0u;  // bound rows

    // ---- row loads in 2 groups of 8; accumulate per pair ----
#pragma unroll
    for (int pg = 0; pg < 2; ++pg) {
        uint4 u[2][4];
#pragma unroll
        for (int pp = 0; pp < 2; ++pp) {
            const int pr2 = pg * 2 + pp;
#pragma unroll
            for (int k = 0; k < 4; ++k) u[pp][k] = LD(sx[pr2][k]);
        }
#pragma unroll
        for (int pp = 0; pp < 2; ++pp) {
            const int pr2 = pg * 2 + pp;
            const uint32 d0 = dd[pr2];
            float aA[8] = {0.f,0.f,0.f,0.f,0.f,0.f,0.f,0.f};
            float aB[8] = {0.f,0.f,0.f,0.f,0.f,0.f,0.f,0.f};
#pragma unroll
            for (int k = 0; k < 4; ++k)
                if (2u * (uint32)k + (uint32)sub >= d0) u[pp][k] = make_uint4(0u,0u,0u,0u);
            ACC(aA, u[pp][0]); ACC(aB, u[pp][1]); ACC(aA, u[pp][2]); ACC(aB, u[pp][3]);

            // leftovers (d > 8): rare (~15% of nodes)
            const uint32* sp = sorted_src + oo[pr2];
            uint32 j = 8;
            for (; j + 8 <= d0; j += 8) {
                uint32 s0 = sp[j + 0 + sub];
                uint32 s1 = sp[j + 2 + sub];
                uint32 s2 = sp[j + 4 + sub];
                uint32 s3 = sp[j + 6 + sub];
                uint4 v0 = LD(s0); uint4 v1 = LD(s1); uint4 v2 = LD(s2); uint4 v3 = LD(s3);
                ACC(aA, v0); ACC(aB, v1); ACC(aA, v2); ACC(aB, v3);
            }
            if (j < d0) {
                const uint32 dm1 = d0 - 1;
                uint32 i0 = j + 0 + sub, i1 = j + 2 + sub, i2 = j + 4 + sub, i3 = j + 6 + sub;
                uint32 s0 = sp[i0 < dm1 ? i0 : dm1];
                uint32 s1 = sp[i1 < dm1 ? i1 : dm1];
                uint32 s2 = sp[i2 < dm1 ? i2 : dm1];
                uint32 s3 = sp[i3 < dm1 ? i3 : dm1];
                uint4 v0 = LD(s0); uint4 v1 = LD(s1); uint4 v2 = LD(s2); uint4 v3 = LD(s3);
                if (i0 >= d0) v0 = make_uint4(0u,0u,0u,0u);
                if (i1 >= d0) v1 = make_uint4(0u,0u,0u,0u);
                if (i2 >= d0) v2 = make_uint4(0u,0u,0u,0u);
                if (i3 >= d0) v3 = make_uint4(0u,0u,0u,0u);
                ACC(aA, v0); ACC(aB, v1); ACC(aA, v2); ACC(aB, v3);
            }
#pragma unroll
            for (int r = 0; r < 8; ++r) {
                aA[r] += aB[r];
                aA[r] += __shfl_xor(aA[r], 16);     // sub0 + sub1
            }
            if (sub == 0) {
                const int nl = wave * 8 + pr2 * 2 + g;
                const float inv = 1.0f / (float)(dd[pr2] > 0u ? dd[pr2] : 1u);
                uint4 w;
                w.x = f2bf(aA[0] * inv) | (f2bf(aA[1] * inv) << 16);
                w.y = f2bf(aA[2] * inv) | (f2bf(aA[3] * inv) << 16);
                w.z = f2bf(aA[4] * inv) | (f2bf(aA[5] * inv) << 16);
                w.w = f2bf(aA[6] * inv) | (f2bf(aA[7] * inv) << 16);
                *reinterpret_cast<uint4*>(&Am[nl * 128 + ((cl ^ (nl & 7)) * 8)]) = w;
            }
        }
    }
#undef LD
#undef ACC
    __syncthreads();

    // ---- GEMM phase: wave = 16 rows x 64 cols (rg = wave>>1, chh = wave&1) ----
    const int rg  = wave >> 1;
    const int chh = wave & 1;
    const int lr  = lane & 15;
    const int lkq = lane >> 4;                  // 0..3
    const int lk  = lkq * 8;
    const int arow = rg * 16 + lr;              // local row

    f32x4 acc[4];
#pragma unroll
    for (int n = 0; n < 4; ++n) acc[n] = (f32x4){0.f, 0.f, 0.f, 0.f};

    // mean half (ks 0..3) from LDS, swizzled
#pragma unroll
    for (int ks = 0; ks < 4; ++ks) {
        const int c0 = lkq + ks * 4;
        short8 a = *reinterpret_cast<const short8*>(
            &Am[arow * 128 + ((c0 ^ (arow & 7)) * 8)]);
#pragma unroll
        for (int n = 0; n < 4; ++n) {
            short8 b = *reinterpret_cast<const short8*>(
                &WcL[((chh * 32 + n * 8 + ks) * 64 + lane) * 8]);
            acc[n] = __builtin_amdgcn_mfma_f32_16x16x32_bf16(a, b, acc[n], 0, 0, 0);
        }
    }
    // nf half (ks 4..7) from global compact AbufN
    const unsigned short* pa = AbufN + (size_t)(row0 + arow) * 128 + lk;
#pragma unroll
    for (int ks = 4; ks < 8; ++ks) {
        short8 a = *reinterpret_cast<const short8*>(pa + (ks - 4) * 32);
#pragma unroll
        for (int n = 0; n < 4; ++n) {
            short8 b = *reinterpret_cast<const short8*>(
                &WcL[((chh * 32 + n * 8 + ks) * 64 + lane) * 8]);
            acc[n] = __builtin_amdgcn_mfma_f32_16x16x32_bf16(a, b, acc[n], 0, 0, 0);
        }
    }

    // epilogue (C/D: col = lane&15, row = (lane>>4)*4 + reg)
    float bv[4];
#pragma unroll
    for (int n = 0; n < 4; ++n) bv[n] = biasc[chh * 64 + n * 16 + lr];

    const int rq = lkq * 4;
#pragma unroll
    for (int r = 0; r < 4; ++r) {
        const int row = row0 + rg * 16 + rq + r;
        if (row < N_NODES) {
            float* orow = out + (size_t)row * D + chh * 64;
#pragma unroll
            for (int n = 0; n < 4; ++n)
                orow[n * 16 + lr] = acc[n][r] + bv[n];
        }
    }
}

extern "C" void kernel_launch(void* const* d_in, const int* in_sizes, int n_in,
                              void* d_out, int out_size, void* d_ws, size_t ws_size,
                              hipStream_t stream) {
    const float* nf    = (const float*)d_in[0];
    const int*   edges = (const int*)d_in[1];
    const float* Wl    = (const float*)d_in[2];
    const float* bl    = (const float*)d_in[3];
    const float* Ws    = (const float*)d_in[4];
    const float* bs    = (const float*)d_in[5];
    float* out = (float*)d_out;

    // workspace layout
    char* p = (char*)d_ws;
    unsigned short* AbufN = (unsigned short*)p; p += (size_t)M_PAD * 128 * sizeof(unsigned short);
    uint32* cntmat     = (uint32*)p; p += (size_t)(SCAN_N + 64) * sizeof(uint32);
    uint32* bpair      = (uint32*)p; p += (size_t)N_EDGES * sizeof(uint32);
    uint32* sorted_src = (uint32*)p; p += (size_t)N_EDGES * sizeof(uint32);
    uint32* off        = (uint32*)p; p += (size_t)(N_NODES + 8) * sizeof(uint32);
    uint64* flags      = (uint64*)p; p += 2048;
    unsigned short* WcF = (unsigned short*)p; p += (size_t)D * 256 * sizeof(unsigned short);
    float* biasc       = (float*)p;

    k1_convert_count<<<1024, 256, 0, stream>>>(nf, AbufN, edges, cntmat, flags);
    k2_scan<<<SCAN_BLK, 256, 0, stream>>>(cntmat, flags, Wl, Ws, bl, bs, WcF, biasc);
    k3_bucket<<<NCH, 256, 0, stream>>>(edges, cntmat, bpair);
    k4_csr<<<NB, 256, 0, stream>>>(bpair, cntmat, off, sorted_src);
    k_fused<<<(N_NODES + 63) / 64, 512, 0, stream>>>(AbufN, off, sorted_src, WcF, biasc, out);
}